// Round 2
// baseline (386.721 us; speedup 1.0000x reference)
//
#include <hip/hip_runtime.h>
#include <hip/hip_bf16.h>
#include <stdint.h>

typedef uint32_t u32;
typedef uint16_t u16;
typedef __attribute__((ext_vector_type(4))) float f32x4;
typedef __attribute__((ext_vector_type(4))) u32 u32x4;

// ---------- helpers ----------
__device__ __forceinline__ u16 f2b(float f) {            // fp32 -> bf16 RNE
  u32 u = __float_as_uint(f);
  return (u16)((u + 0x7FFFu + ((u >> 16) & 1u)) >> 16);
}
__device__ __forceinline__ float b2f(u16 b) {
  return __uint_as_float(((u32)b) << 16);
}

// async global->LDS, 16B per lane; lds dest must be the WAVE-uniform base.
__device__ __forceinline__ void gl_lds16(const void* g, const void* l) {
  __builtin_amdgcn_global_load_lds(
      (__attribute__((address_space(1))) void*)(void*)g,
      (__attribute__((address_space(3))) void*)(void*)l, 16, 0, 0);
}

// D = A(16x32 bf16) * B(32x16 bf16) + D, fp32 acc.
// s_nop 1 covers VALU-write -> MFMA-read hazard on inputs.
__device__ __forceinline__ void mfma16(f32x4& d, u32x4 a, u32x4 b) {
  asm("s_nop 1\n\tv_mfma_f32_16x16x32_bf16 %0, %1, %2, %0"
      : "+v"(d) : "v"(a), "v"(b));
}

// Register-tied hazard fence: guarantees >=16 stall cycles between the MFMA
// that wrote x and any VALU read of x (data dependence forces placement).
#define FENCE4(x) asm volatile("s_nop 7\n\ts_nop 7" : "+v"(x))

#define NWIN 512
#define NTOK 196
#define NHEAD 6
#define HD 32
#define NPAD 208               // 13*16
#define N_X 19267584u          // 512*196*192

// ---------- prep kernels ----------
__global__ void k_prep_x(const float* __restrict__ x, u16* __restrict__ xb, int n4) {
  int i = blockIdx.x * blockDim.x + threadIdx.x;
  int stride = gridDim.x * blockDim.x;
  for (; i < n4; i += stride) {
    float4 v = ((const float4*)x)[i];
    ushort4 o; o.x = f2b(v.x); o.y = f2b(v.y); o.z = f2b(v.z); o.w = f2b(v.w);
    ((ushort4*)xb)[i] = o;
  }
}

__global__ void k_prep_w(const float* __restrict__ wq, const float* __restrict__ wp,
                         u16* __restrict__ wqb, u16* __restrict__ wpb) {
  int i = blockIdx.x * 256 + threadIdx.x;   // 36864 float4 units total
  if (i < 27648) {
    float4 v = ((const float4*)wq)[i];
    ushort4 o; o.x = f2b(v.x); o.y = f2b(v.y); o.z = f2b(v.z); o.w = f2b(v.w);
    ((ushort4*)wqb)[i] = o;
  } else if (i < 36864) {
    int j = i - 27648;
    float4 v = ((const float4*)wp)[j];
    ushort4 o; o.x = f2b(v.x); o.y = f2b(v.y); o.z = f2b(v.z); o.w = f2b(v.w);
    ((ushort4*)wpb)[j] = o;
  }
}

// fused (bias_table gathered by rel_index) + mask -> bf16 [64][6][208][208]
// pads (row>=196 or col>=196) = -30000 so padded columns softmax to 0.
__global__ void k_prep_bm(const float* __restrict__ bias_table,
                          const float* __restrict__ mask,
                          const int* __restrict__ rel,
                          u16* __restrict__ bm) {
  u32 i = blockIdx.x * 256 + threadIdx.x;        // 64*6*208*208 exact
  u32 j = i % 208; u32 t = i / 208;
  u32 qi = t % 208; t /= 208;
  u32 h = t % 6; u32 g = t / 6;
  if (g >= 64) return;
  float v;
  if (qi < 196 && j < 196) {
    int r = rel[qi * 196 + j];
    v = bias_table[r * 6 + h] + mask[(g * 196 + qi) * 196 + j];
  } else v = -30000.0f;
  bm[i] = f2b(v);
}

// zero V pad rows (tok 196..223) in chunked vT layout [wh][mc][d][8]
__global__ void k_prep_vpad(u16* __restrict__ vT) {
  u32 i = blockIdx.x * 256 + threadIdx.x;        // 3072*896 exact
  u32 wh = i / 896; u32 rem = i % 896;
  u32 tok = 196 + rem / 32; u32 d = rem % 32;
  vT[wh * 7168 + (tok >> 3) * 256 + d * 8 + (tok & 7)] = 0;
}

// ---------- kernel 1: qkv GEMM  M=100352 N=576 K=192 ----------
// A staged to LDS with XOR slot swizzle; B frags straight from L2.
__global__ __launch_bounds__(256) void k_qkv(
    const u16* __restrict__ xb, const u16* __restrict__ wq,
    u16* __restrict__ q_ws, u16* __restrict__ k_ws, u16* __restrict__ vT_ws) {
  __shared__ u16 A_lds[128 * 24 * 8];   // [row][slot][8], slot = kc ^ (row&7)
  u32 orig = blockIdx.x;                             // 7056 blocks
  u32 wg = (orig & 7) * 882 + (orig >> 3);           // bijective XCD swizzle
  u32 mblk = wg / 9, nb = wg - mblk * 9;
  u32 m0 = mblk * 128, n0 = nb * 64;
  u32 tid = threadIdx.x, lane = tid & 63, wv = tid >> 6;
  u32 wr = wv >> 1, wc = wv & 1;
  u32 g = lane >> 4, c16 = lane & 15;

  #pragma unroll
  for (u32 i = 0; i < 12; ++i) {                     // 48KB A tile
    u32 Lb = (wv * 12 + i) * 1024;
    u32 L = Lb + lane * 16;
    u32 r = L / 384;
    u32 s = (L - r * 384) >> 4;
    u32 kc = s ^ (r & 7);
    gl_lds16(xb + (m0 + r) * 192 + kc * 8, (const char*)A_lds + Lb);
  }
  u32x4 bfr[6][2];
  #pragma unroll
  for (int n = 0; n < 2; ++n) {
    u32 ccol = n0 + wc * 32 + n * 16 + c16;
    const u16* bp = wq + ccol * 192 + g * 8;
    #pragma unroll
    for (int kk = 0; kk < 6; ++kk) bfr[kk][n] = *(const u32x4*)(bp + kk * 32);
  }
  f32x4 acc[4][2];
  #pragma unroll
  for (int m = 0; m < 4; ++m) { acc[m][0] = 0.f; acc[m][1] = 0.f; }
  __syncthreads();
  #pragma unroll
  for (int kk = 0; kk < 6; ++kk) {
    #pragma unroll
    for (int m = 0; m < 4; ++m) {
      u32 row = wr * 64 + m * 16 + c16;
      u32 kc = (u32)(kk * 4) + g;
      u32x4 a = *(const u32x4*)&A_lds[(row * 24 + (kc ^ (row & 7))) * 8];
      mfma16(acc[m][0], a, bfr[kk][0]);
      mfma16(acc[m][1], a, bfr[kk][1]);
    }
  }
  #pragma unroll
  for (int m = 0; m < 4; ++m) { FENCE4(acc[m][0]); FENCE4(acc[m][1]); }
  u32 three = n0 / 192;                  // block-uniform: q/k/v
  u32 cbase = n0 - three * 192 + wc * 32 + c16;
  #pragma unroll
  for (int m = 0; m < 4; ++m) {
    #pragma unroll
    for (int r = 0; r < 4; ++r) {
      u32 M = m0 + wr * 64 + m * 16 + g * 4 + r;
      u32 w = M / 196, tok = M - w * 196;
      #pragma unroll
      for (int n = 0; n < 2; ++n) {
        u32 c192 = cbase + n * 16;
        u32 hh = c192 >> 5, d = c192 & 31;
        u32 whi = w * 6 + hh;
        float v = acc[m][n][r];
        if (three == 0)
          q_ws[(whi * 196 + tok) * 32 + d] = f2b(v * 0.17677669529663687f);
        else if (three == 1)
          k_ws[(whi * 196 + tok) * 32 + d] = f2b(v);
        else
          vT_ws[whi * 7168 + (tok >> 3) * 256 + d * 8 + (tok & 7)] = f2b(v);
      }
    }
  }
}

// ---------- kernel 2: fused attention per (window, head) ----------
// 13 waves; wave wt owns q rows [wt*16, wt*16+16)
__global__ __launch_bounds__(832) void k_attn(
    const u16* __restrict__ q_ws, const u16* __restrict__ k_ws,
    const u16* __restrict__ vT_ws, const u16* __restrict__ bm,
    u16* __restrict__ attnout) {
  __shared__ u16 qL[4 * 224 * 8];   // [kc][tok][8]  14336B
  __shared__ u16 kL[4 * 224 * 8];
  __shared__ u16 vL[28 * 32 * 8];   // [mc][d][8]    14336B
  __shared__ u16 pS[13 * 512];      // per-wave P scratch (A-frag order)

  u32 b = blockIdx.x;               // 3072
  u32 h = b % 6; u32 wg = b / 6;
  u32 gm = wg >> 3, rep = wg & 7;
  u32 w = rep * 64 + gm;            // w % 64 == gm (mask group)
  u32 whi = w * 6 + h;
  u32 tid = threadIdx.x, lane = tid & 63, wv = tid >> 6;
  u32 g = lane >> 4, c16 = lane & 15;

  const u16* qg = q_ws + whi * 6272;
  const u16* kg = k_ws + whi * 6272;
  const u16* vg = vT_ws + whi * 7168;
  for (u32 idx = wv; idx < 42; idx += 13) {
    u32 bufi = idx < 14 ? 0u : (idx < 28 ? 1u : 2u);
    u32 i = idx - bufi * 14;
    u32 Lb = i * 1024;
    if (bufi < 2) {                          // q/k: chunk-scatter via source
      u32 s = i * 64 + lane;                 // slot = kc*224 + tok
      u32 kc = s / 224, tok = s - kc * 224;
      u32 tokc = tok < 196 ? tok : 0;        // clamp: finite garbage in pads
      gl_lds16((bufi ? kg : qg) + tokc * 32 + kc * 8,
               (const char*)(bufi ? kL : qL) + Lb);
    } else {                                 // v: linear copy
      gl_lds16(vg + i * 512 + lane * 8, (const char*)vL + Lb);
    }
  }
  __syncthreads();

  u32 wt = wv;                                   // row tile 0..12
  u32x4 qf = *(const u32x4*)&qL[(g * 224 + wt * 16 + c16) * 8];
  const u16* bmb = bm + (gm * 6 + h) * 208u * 208u;

  f32x4 S[13];
  #pragma unroll
  for (int t = 0; t < 13; ++t) {
    f32x4 cin;
    #pragma unroll
    for (int r = 0; r < 4; ++r)
      cin[r] = b2f(bmb[(wt * 16 + g * 4 + r) * 208 + t * 16 + c16]);
    u32x4 kf = *(const u32x4*)&kL[(g * 224 + t * 16 + c16) * 8];
    S[t] = cin;
    mfma16(S[t], qf, kf);                      // S = q*k^T + (bias+mask)
  }
  FENCE4(S[10]); FENCE4(S[11]); FENCE4(S[12]);

  float sm[4];
  #pragma unroll
  for (int r = 0; r < 4; ++r) {                // softmax over 208 cols
    float m = S[0][r];
    #pragma unroll
    for (int t = 1; t < 13; ++t) m = fmaxf(m, S[t][r]);
    m = fmaxf(m, __shfl_xor(m, 1));
    m = fmaxf(m, __shfl_xor(m, 2));
    m = fmaxf(m, __shfl_xor(m, 4));
    m = fmaxf(m, __shfl_xor(m, 8));
    float s = 0.f;
    #pragma unroll
    for (int t = 0; t < 13; ++t) { float e = __expf(S[t][r] - m); S[t][r] = e; s += e; }
    s += __shfl_xor(s, 1); s += __shfl_xor(s, 2);
    s += __shfl_xor(s, 4); s += __shfl_xor(s, 8);
    sm[r] = s;
  }

  u16* myS = pS + wv * 512;
  f32x4 o[2];
  o[0] = 0.f; o[1] = 0.f;
  #pragma unroll
  for (int c = 0; c < 7; ++c) {                // PV over K chunks of 32
    #pragma unroll
    for (int half = 0; half < 2; ++half) {
      int t = 2 * c + half;
      u32 kc2 = (c16 >> 3) + 2 * half;
      u32 j = c16 & 7;
      #pragma unroll
      for (int r = 0; r < 4; ++r) {
        u32 row = g * 4 + r;
        myS[(kc2 * 16 + row) * 8 + j] = (t < 13) ? f2b(S[t][r]) : (u16)0;
      }
    }
    asm volatile("" ::: "memory");             // order ds_write(u16) vs ds_read(b128)
    u32x4 pf = *(const u32x4*)&myS[lane * 8];  // A-frag = linear lane*16
    #pragma unroll
    for (int n = 0; n < 2; ++n) {
      u32x4 vf = *(const u32x4*)&vL[((c * 4 + g) * 32 + n * 16 + c16) * 8];
      mfma16(o[n], pf, vf);
    }
  }
  FENCE4(o[0]); FENCE4(o[1]);

  #pragma unroll
  for (int r = 0; r < 4; ++r) {
    u32 tok = wt * 16 + g * 4 + r;
    if (tok < 196) {
      float inv = 1.0f / sm[r];
      #pragma unroll
      for (int n = 0; n < 2; ++n)
        attnout[(w * 196 + tok) * 192 + h * 32 + n * 16 + c16] = f2b(o[n][r] * inv);
    }
  }
}

// ---------- kernel 3: proj GEMM  M=100352 N=192 K=192, fp32 out ----------
__global__ __launch_bounds__(256) void k_proj(
    const u16* __restrict__ ab, const u16* __restrict__ wp,
    const float* __restrict__ bpj, float* __restrict__ out) {
  __shared__ u16 A_lds[128 * 24 * 8];
  u32 orig = blockIdx.x;                         // 2352 blocks
  u32 wg = (orig & 7) * 294 + (orig >> 3);
  u32 mblk = wg / 3, nb = wg - mblk * 3;
  u32 m0 = mblk * 128, n0 = nb * 64;
  u32 tid = threadIdx.x, lane = tid & 63, wv = tid >> 6;
  u32 wr = wv >> 1, wc = wv & 1;
  u32 g = lane >> 4, c16 = lane & 15;

  #pragma unroll
  for (u32 i = 0; i < 12; ++i) {
    u32 Lb = (wv * 12 + i) * 1024;
    u32 L = Lb + lane * 16;
    u32 r = L / 384;
    u32 s = (L - r * 384) >> 4;
    u32 kc = s ^ (r & 7);
    gl_lds16(ab + (m0 + r) * 192 + kc * 8, (const char*)A_lds + Lb);
  }
  u32x4 bfr[6][2];
  #pragma unroll
  for (int n = 0; n < 2; ++n) {
    u32 ccol = n0 + wc * 32 + n * 16 + c16;
    const u16* bp = wp + ccol * 192 + g * 8;
    #pragma unroll
    for (int kk = 0; kk < 6; ++kk) bfr[kk][n] = *(const u32x4*)(bp + kk * 32);
  }
  f32x4 acc[4][2];
  #pragma unroll
  for (int m = 0; m < 4; ++m) { acc[m][0] = 0.f; acc[m][1] = 0.f; }
  __syncthreads();
  #pragma unroll
  for (int kk = 0; kk < 6; ++kk) {
    #pragma unroll
    for (int m = 0; m < 4; ++m) {
      u32 row = wr * 64 + m * 16 + c16;
      u32 kc = (u32)(kk * 4) + g;
      u32x4 a = *(const u32x4*)&A_lds[(row * 24 + (kc ^ (row & 7))) * 8];
      mfma16(acc[m][0], a, bfr[kk][0]);
      mfma16(acc[m][1], a, bfr[kk][1]);
    }
  }
  #pragma unroll
  for (int m = 0; m < 4; ++m) { FENCE4(acc[m][0]); FENCE4(acc[m][1]); }
  #pragma unroll
  for (int m = 0; m < 4; ++m) {
    #pragma unroll
    for (int r = 0; r < 4; ++r) {
      u32 M = m0 + wr * 64 + m * 16 + g * 4 + r;
      #pragma unroll
      for (int n = 0; n < 2; ++n) {
        u32 col = n0 + wc * 32 + n * 16 + c16;
        out[M * 192 + col] = acc[m][n][r] + bpj[col];
      }
    }
  }
}

// ---------- launch ----------
extern "C" void kernel_launch(void* const* d_in, const int* in_sizes, int n_in,
                              void* d_out, int out_size, void* d_ws, size_t ws_size,
                              hipStream_t stream) {
  const float* x         = (const float*)d_in[0];
  const float* w_qkv     = (const float*)d_in[1];
  const float* w_proj    = (const float*)d_in[2];
  const float* b_proj    = (const float*)d_in[3];
  const float* bias_tab  = (const float*)d_in[4];
  const float* mask      = (const float*)d_in[5];
  const int*   rel       = (const int*)d_in[6];
  float* out             = (float*)d_out;

  u16* xb    = (u16*)d_ws;
  u16* wqb   = xb + N_X;
  u16* wpb   = wqb + 110592;
  u16* q_ws  = wpb + 36864;
  u16* k_ws  = q_ws + N_X;
  u16* vT_ws = k_ws + N_X;
  u16* bmt   = vT_ws + 22020096u;
  u16* attnout = xb;                 // x_bf dead after k_qkv -> alias

  k_prep_x<<<2048, 256, 0, stream>>>(x, xb, (int)(N_X / 4));
  k_prep_w<<<144, 256, 0, stream>>>(w_qkv, w_proj, wqb, wpb);
  k_prep_bm<<<64896, 256, 0, stream>>>(bias_tab, mask, rel, bmt);
  k_prep_vpad<<<10752, 256, 0, stream>>>(vT_ws);
  k_qkv<<<7056, 256, 0, stream>>>(xb, wqb, q_ws, k_ws, vT_ws);
  k_attn<<<3072, 832, 0, stream>>>(q_ws, k_ws, vT_ws, bmt, attnout);
  k_proj<<<2352, 256, 0, stream>>>(attnout, wpb, b_proj, out);
}

// Round 8
// 384.556 us; speedup vs baseline: 1.0056x; 1.0056x over previous
//
#include <hip/hip_runtime.h>
#include <hip/hip_bf16.h>
#include <stdint.h>

typedef uint32_t u32;
typedef uint16_t u16;
typedef __attribute__((ext_vector_type(4))) float f32x4;
typedef __attribute__((ext_vector_type(4))) u32 u32x4;

// ---------- helpers ----------
__device__ __forceinline__ u16 f2b(float f) {            // fp32 -> bf16 RNE
  u32 u = __float_as_uint(f);
  return (u16)((u + 0x7FFFu + ((u >> 16) & 1u)) >> 16);
}

// async global->LDS, 16B per lane; lds dest must be the WAVE-uniform base.
__device__ __forceinline__ void gl_lds16(const void* g, const void* l) {
  __builtin_amdgcn_global_load_lds(
      (__attribute__((address_space(1))) void*)(void*)g,
      (__attribute__((address_space(3))) void*)(void*)l, 16, 0, 0);
}

// D += A(16x32 bf16) * B(32x16 bf16), fp32 acc. s_nop 1 covers VALU->MFMA src.
__device__ __forceinline__ void mfma16(f32x4& d, u32x4 a, u32x4 b) {
  asm("s_nop 1\n\tv_mfma_f32_16x16x32_bf16 %0, %1, %2, %0"
      : "+v"(d) : "v"(a), "v"(b));
}

// Register-tied hazard fence (MFMA write -> VALU read of same regs).
#define FENCE4(x) asm volatile("s_nop 7\n\ts_nop 7" : "+v"(x))

#define N_X 19267584u          // 512*196*192
#define LOG2E 1.4426950408889634f
#define SCALE_Q (0.17677669529663687f * 1.4426950408889634f)
#define NEGBIG -43281.0f       // -30000 * log2e

// ---------- prep: x / w_qkv / w_proj -> bf16 ----------
__global__ void k_prep_xw(const float* __restrict__ x, const float* __restrict__ wq,
                          const float* __restrict__ wp, u16* __restrict__ xb,
                          u16* __restrict__ wqb, u16* __restrict__ wpb) {
  const int NX4 = 4816896;   // N_X/4
  const int TOT = NX4 + 27648 + 9216;
  int i = blockIdx.x * 256 + threadIdx.x;
  int stride = gridDim.x * 256;
  for (; i < TOT; i += stride) {
    const float4* src; ushort4* dst;
    if (i < NX4)                { src = (const float4*)x  + i;             dst = (ushort4*)xb  + i; }
    else if (i < NX4 + 27648)   { src = (const float4*)wq + (i - NX4);     dst = (ushort4*)wqb + (i - NX4); }
    else                        { src = (const float4*)wp + (i-NX4-27648); dst = (ushort4*)wpb + (i-NX4-27648); }
    float4 v = *src;
    ushort4 o; o.x = f2b(v.x); o.y = f2b(v.y); o.z = f2b(v.z); o.w = f2b(v.w);
    *dst = o;
  }
}

// ---------- prep: (bias gather + mask) * log2e -> bf16, TRANSPOSED frag order
// bmT[gh=gm*6+h][tile=t*13+wt][256]: frag elem (row=tok=t*16+g*4+r, col=qrow=wt*16+c16)
// at [tile*256 + (g*16+c16)*4 + r]. Pads (tok>=196 || qrow>=196) = NEGBIG.
__global__ void k_prep_bm(const float* __restrict__ bias_table,
                          const float* __restrict__ mask,
                          const int* __restrict__ rel,
                          u16* __restrict__ bmT) {
  u32 gh = blockIdx.y;                    // 384
  u32 gm = gh / 6, h = gh - gm * 6;
  u32 tile = blockIdx.x;                  // 169
  u32 t = tile / 13, wt = tile - t * 13;
  u32 tid = threadIdx.x;                  // 256
  u32 fl = tid >> 2, r = tid & 3;
  u32 g = fl >> 4, c16 = fl & 15;
  u32 tok = t * 16 + g * 4 + r;
  u32 qrow = wt * 16 + c16;
  float v;
  if (tok < 196 && qrow < 196)
    v = (bias_table[rel[qrow * 196 + tok] * 6 + h] +
         mask[(gm * 196 + qrow) * 196 + tok]) * LOG2E;
  else v = NEGBIG;
  bmT[(gh * 169 + tile) * 256 + tid] = f2b(v);
}

// ---------- kernel 1: qkv GEMM  M=100352 N=576 K=192 ----------
// Outputs written in MFMA fragment order:
//  q/k: [whi][tile=tok>>4][lane=(d>>3)*16+(tok&15)][j=d&7]   (6656 u16/whi)
//  v:   [whi][tile=(tok>>5)*2+(d>>4)][lane=((tok>>3)&3)*16+(d&15)][j=tok&7] (7168)
__global__ __launch_bounds__(256) void k_qkv(
    const u16* __restrict__ xb, const u16* __restrict__ wq,
    u16* __restrict__ q_ws, u16* __restrict__ k_ws, u16* __restrict__ vT_ws) {
  __shared__ u16 A_lds[128 * 24 * 8];   // [row][slot][8], slot = kc ^ (row&7)
  u32 orig = blockIdx.x;                             // 7056 blocks
  u32 wg = (orig & 7) * 882 + (orig >> 3);           // bijective XCD swizzle
  u32 mblk = wg / 9, nb = wg - mblk * 9;
  u32 m0 = mblk * 128;
  u32 tid = threadIdx.x, lane = tid & 63, wv = tid >> 6;
  u32 wr = wv >> 1, wc = wv & 1;
  u32 g = lane >> 4, c16 = lane & 15;

  #pragma unroll
  for (u32 i = 0; i < 12; ++i) {                     // 48KB A tile
    u32 Lb = (wv * 12 + i) * 1024;
    u32 L = Lb + lane * 16;
    u32 rr = L / 384;
    u32 s = (L - rr * 384) >> 4;
    u32 kc = s ^ (rr & 7);
    gl_lds16(xb + (m0 + rr) * 192 + kc * 8, (const char*)A_lds + Lb);
  }
  u32x4 bfr[6][2];
  #pragma unroll
  for (int n = 0; n < 2; ++n) {
    u32 ccol = nb * 64 + wc * 32 + n * 16 + c16;
    const u16* bp = wq + ccol * 192 + g * 8;
    #pragma unroll
    for (int kk = 0; kk < 6; ++kk) bfr[kk][n] = *(const u32x4*)(bp + kk * 32);
  }
  f32x4 acc[4][2];
  #pragma unroll
  for (int m = 0; m < 4; ++m) { acc[m][0] = 0.f; acc[m][1] = 0.f; }
  __syncthreads();
  #pragma unroll
  for (int kk = 0; kk < 6; ++kk) {
    #pragma unroll
    for (int m = 0; m < 4; ++m) {
      u32 row = wr * 64 + m * 16 + c16;
      u32 kc = (u32)(kk * 4) + g;
      u32x4 a = *(const u32x4*)&A_lds[(row * 24 + (kc ^ (row & 7))) * 8];
      mfma16(acc[m][0], a, bfr[kk][0]);
      mfma16(acc[m][1], a, bfr[kk][1]);
    }
  }
  #pragma unroll
  for (int m = 0; m < 4; ++m) { FENCE4(acc[m][0]); FENCE4(acc[m][1]); }
  u32 three = nb / 3;                        // 0:q 1:k 2:v (block-uniform)
  u32 cb = (nb - three * 3) * 64 + wc * 32 + c16;
  #pragma unroll
  for (int m = 0; m < 4; ++m) {
    #pragma unroll
    for (int r = 0; r < 4; ++r) {
      u32 M = m0 + wr * 64 + m * 16 + g * 4 + r;
      u32 w = M / 196, tok = M - w * 196;
      #pragma unroll
      for (int n = 0; n < 2; ++n) {
        u32 c192 = cb + n * 16;
        u32 hh = c192 >> 5, d = c192 & 31;
        u32 whi = w * 6 + hh;
        float v = acc[m][n][r];
        if (three == 0)
          q_ws[whi * 6656 + (tok >> 4) * 512 + ((d >> 3) * 16 + (tok & 15)) * 8 + (d & 7)]
              = f2b(v * SCALE_Q);
        else if (three == 1)
          k_ws[whi * 6656 + (tok >> 4) * 512 + ((d >> 3) * 16 + (tok & 15)) * 8 + (d & 7)]
              = f2b(v);
        else
          vT_ws[whi * 7168 + ((tok >> 5) * 2 + (d >> 4)) * 512 +
                (((tok >> 3) & 3) * 16 + (d & 15)) * 8 + (tok & 7)] = f2b(v);
      }
    }
  }
}

// ---------- kernel 2: fused attention, swapped QK^T, 3 (w,h) per block ----------
__global__ __launch_bounds__(832, 4) void k_attn(
    const u16* __restrict__ q_ws, const u16* __restrict__ k_ws,
    const u16* __restrict__ vT_ws, const u16* __restrict__ bmT,
    u16* __restrict__ attnout) {
  __shared__ u16 kL[3][13 * 512];     // 3 x 13KB, frag tiles
  __shared__ u16 vL[3][14 * 512];     // 3 x 14KB
  __shared__ u16 pS[13 * 640];        // per-wave 1280B P scratch (80B rows)
  u32 b = blockIdx.x;                 // 1024
  u32 whi0 = b * 3;
  u32 w = whi0 / 6;
  u32 h0 = whi0 - w * 6;              // 0 or 3
  u32 gm = w & 63;                    // mask group
  u32 tid = threadIdx.x, lane = tid & 63, wv = tid >> 6;
  u32 g = lane >> 4, c16 = lane & 15;

  for (u32 idx = wv; idx < 81; idx += 13) {     // stage K,V for 3 whis
    u32 wl = idx / 27, i = idx - wl * 27;
    if (i < 13)
      gl_lds16(k_ws + (whi0 + wl) * 6656 + i * 512 + lane * 8,
               (const char*)kL[wl] + i * 1024);
    else
      gl_lds16(vT_ws + (whi0 + wl) * 7168 + (i - 13) * 512 + lane * 8,
               (const char*)vL[wl] + (i - 13) * 1024);
  }
  __syncthreads();

  char* mysb = (char*)pS + wv * 1280;
  #pragma unroll 1
  for (u32 ph = 0; ph < 3; ++ph) {
    u32 whi = whi0 + ph, h = h0 + ph;
    const u16* bp = bmT + ((gm * 6 + h) * 169u + wv) * 256 + lane * 4;
    u32x4 qf = *(const u32x4*)(q_ws + whi * 6656 + wv * 512 + lane * 8);

    f32x4 S[13];
    __builtin_amdgcn_s_setprio(1);
    #pragma unroll
    for (int t = 0; t < 13; ++t) {
      uint2 br = *(const uint2*)(bp + t * 3328);
      f32x4 cin;
      cin[0] = __uint_as_float(br.x << 16);
      cin[1] = __uint_as_float(br.x & 0xFFFF0000u);
      cin[2] = __uint_as_float(br.y << 16);
      cin[3] = __uint_as_float(br.y & 0xFFFF0000u);
      u32x4 kf = *(const u32x4*)((const char*)kL[ph] + t * 1024 + lane * 16);
      S[t] = cin;
      mfma16(S[t], kf, qf);             // S^T = K·Q^T + (bias+mask)^T, log2 domain
    }
    __builtin_amdgcn_s_setprio(0);
    FENCE4(S[11]); FENCE4(S[12]);

    // softmax over tokens: regs (52) + cross-g (xor 16, 32); qrow = c16
    f32x4 M4 = S[0];
    #pragma unroll
    for (int t = 1; t < 13; ++t) {
      M4[0] = fmaxf(M4[0], S[t][0]); M4[1] = fmaxf(M4[1], S[t][1]);
      M4[2] = fmaxf(M4[2], S[t][2]); M4[3] = fmaxf(M4[3], S[t][3]);
    }
    float m = fmaxf(fmaxf(M4[0], M4[1]), fmaxf(M4[2], M4[3]));
    m = fmaxf(m, __shfl_xor(m, 16));
    m = fmaxf(m, __shfl_xor(m, 32));
    f32x4 A4; A4 = 0.f;
    #pragma unroll
    for (int t = 0; t < 13; ++t) {
      S[t][0] = exp2f(S[t][0] - m); S[t][1] = exp2f(S[t][1] - m);
      S[t][2] = exp2f(S[t][2] - m); S[t][3] = exp2f(S[t][3] - m);
      A4 += S[t];
    }
    float s = (A4[0] + A4[1]) + (A4[2] + A4[3]);
    s += __shfl_xor(s, 16);
    s += __shfl_xor(s, 32);
    float inv = 1.0f / s;
    float invr[4];
    #pragma unroll
    for (int r = 0; r < 4; ++r) invr[r] = __shfl(inv, (int)(g * 4 + r));

    // PV: pack P -> bf16 (cvt_pk), transpose via per-wave LDS (80B rows)
    f32x4 o0, o1; o0 = 0.f; o1 = 0.f;
    __builtin_amdgcn_s_setprio(1);
    #pragma unroll
    for (int c = 0; c < 7; ++c) {
      #pragma unroll
      for (int half = 0; half < 2; ++half) {
        int t = 2 * c + half;
        uint2 pw;
        if (t < 13) {
          asm("v_cvt_pk_bf16_f32 %0, %1, %2" : "=v"(pw.x) : "v"(S[t][0]), "v"(S[t][1]));
          asm("v_cvt_pk_bf16_f32 %0, %1, %2" : "=v"(pw.y) : "v"(S[t][2]), "v"(S[t][3]));
        } else { pw.x = 0u; pw.y = 0u; }
        *(uint2*)(mysb + c16 * 80 + half * 32 + g * 8) = pw;
      }
      asm volatile("" ::: "memory");
      u32x4 pf = *(const u32x4*)(mysb + c16 * 80 + g * 16);
      u32x4 vf0 = *(const u32x4*)((const char*)vL[ph] + (c * 2 + 0) * 1024 + lane * 16);
      mfma16(o0, pf, vf0);
      u32x4 vf1 = *(const u32x4*)((const char*)vL[ph] + (c * 2 + 1) * 1024 + lane * 16);
      mfma16(o1, pf, vf1);
      asm volatile("" ::: "memory");
    }
    __builtin_amdgcn_s_setprio(0);
    FENCE4(o0); FENCE4(o1);

    #pragma unroll
    for (int r = 0; r < 4; ++r) {
      u32 tok = wv * 16 + g * 4 + r;
      if (tok < 196) {
        u32 base = (w * 196 + tok) * 192 + h * 32 + c16;
        attnout[base]      = f2b(o0[r] * invr[r]);
        attnout[base + 16] = f2b(o1[r] * invr[r]);
      }
    }
  }
}

// ---------- kernel 3: proj GEMM  M=100352 N=192 K=192, fp32 out ----------
__global__ __launch_bounds__(256) void k_proj(
    const u16* __restrict__ ab, const u16* __restrict__ wp,
    const float* __restrict__ bpj, float* __restrict__ out) {
  __shared__ u16 A_lds[128 * 24 * 8];
  u32 orig = blockIdx.x;                         // 2352 blocks
  u32 wg = (orig & 7) * 294 + (orig >> 3);
  u32 mblk = wg / 3, nb = wg - mblk * 3;
  u32 m0 = mblk * 128, n0 = nb * 64;
  u32 tid = threadIdx.x, lane = tid & 63, wv = tid >> 6;
  u32 wr = wv >> 1, wc = wv & 1;
  u32 g = lane >> 4, c16 = lane & 15;

  #pragma unroll
  for (u32 i = 0; i < 12; ++i) {
    u32 Lb = (wv * 12 + i) * 1024;
    u32 L = Lb + lane * 16;
    u32 rr = L / 384;
    u32 s = (L - rr * 384) >> 4;
    u32 kc = s ^ (rr & 7);
    gl_lds16(ab + (m0 + rr) * 192 + kc * 8, (const char*)A_lds + Lb);
  }
  u32x4 bfr[6][2];
  #pragma unroll
  for (int n = 0; n < 2; ++n) {
    u32 ccol = n0 + wc * 32 + n * 16 + c16;
    const u16* bp = wp + ccol * 192 + g * 8;
    #pragma unroll
    for (int kk = 0; kk < 6; ++kk) bfr[kk][n] = *(const u32x4*)(bp + kk * 32);
  }
  f32x4 acc[4][2];
  #pragma unroll
  for (int m = 0; m < 4; ++m) { acc[m][0] = 0.f; acc[m][1] = 0.f; }
  __syncthreads();
  #pragma unroll
  for (int kk = 0; kk < 6; ++kk) {
    #pragma unroll
    for (int m = 0; m < 4; ++m) {
      u32 row = wr * 64 + m * 16 + c16;
      u32 kc = (u32)(kk * 4) + g;
      u32x4 a = *(const u32x4*)&A_lds[(row * 24 + (kc ^ (row & 7))) * 8];
      mfma16(acc[m][0], a, bfr[kk][0]);
      mfma16(acc[m][1], a, bfr[kk][1]);
    }
  }
  #pragma unroll
  for (int m = 0; m < 4; ++m) { FENCE4(acc[m][0]); FENCE4(acc[m][1]); }
  #pragma unroll
  for (int m = 0; m < 4; ++m) {
    #pragma unroll
    for (int r = 0; r < 4; ++r) {
      u32 M = m0 + wr * 64 + m * 16 + g * 4 + r;
      #pragma unroll
      for (int n = 0; n < 2; ++n) {
        u32 col = n0 + wc * 32 + n * 16 + c16;
        out[M * 192 + col] = acc[m][n][r] + bpj[col];
      }
    }
  }
}

// ---------- launch ----------
extern "C" void kernel_launch(void* const* d_in, const int* in_sizes, int n_in,
                              void* d_out, int out_size, void* d_ws, size_t ws_size,
                              hipStream_t stream) {
  const float* x        = (const float*)d_in[0];
  const float* w_qkv    = (const float*)d_in[1];
  const float* w_proj   = (const float*)d_in[2];
  const float* b_proj   = (const float*)d_in[3];
  const float* bias_tab = (const float*)d_in[4];
  const float* mask     = (const float*)d_in[5];
  const int*   rel      = (const int*)d_in[6];
  float* out            = (float*)d_out;

  u16* wqb   = (u16*)d_ws;                      //   110592
  u16* wpb   = wqb + 110592;                    //    36864
  u16* q_ws  = wpb + 36864;                     // 20447232 (3072*6656)
  u16* k_ws  = q_ws + 20447232u;                // 20447232
  u16* vT_ws = k_ws + 20447232u;                // 22020096 (3072*7168)
  u16* X     = vT_ws + 22020096u;               // region X
  u16* xb      = X;                             // 19267584 (dead after k_qkv)
  u16* bmt     = X;                             // 16613376 (written after k_qkv)
  u16* attnout = X + 16613376u;                 // 19267584

  k_prep_xw<<<2048, 256, 0, stream>>>(x, w_qkv, w_proj, xb, wqb, wpb);
  k_qkv<<<7056, 256, 0, stream>>>(xb, wqb, q_ws, k_ws, vT_ws);
  k_prep_bm<<<dim3(169, 384), 256, 0, stream>>>(bias_tab, mask, rel, bmt);
  k_attn<<<1024, 832, 0, stream>>>(q_ws, k_ws, vT_ws, bmt, attnout);
  k_proj<<<2352, 256, 0, stream>>>(attnout, wpb, b_proj, out);
}